// Round 15
// baseline (379.943 us; speedup 1.0000x reference)
//
#include <hip/hip_runtime.h>
#include <hip/hip_bf16.h>

#define N_NODES 100000
#define N_EDGES 3200000
#define FEAT 256
#define HIDDEN 32
#define EMBED 16
#define NPB 128                                // nodes per bin
#define NBIN ((N_NODES + NPB - 1) / NPB)       // 782
#define CAPB 4608                              // bin capacity (mean 4096 + 8 sigma)
#define OCAP 8192                              // overflow list capacity
#define GR 128                                 // gemm1 tile rows
#define GS 68                                  // LDS row stride (floats)
#define G1N 32                                 // nodes per gather1 block
#define G1CAP 2048                             // LDS entries
#define G2N 64                                 // nodes per gather2 block
#define G2CAP 3072                             // LDS entries
#define PEPB 3072                              // edges per partition block
#define PBLK ((N_EDGES + PEPB - 1) / PEPB)     // 1042
#define NSK (NPB * 8)                          // sub-keys: node x 8 src-tiles

// ---------------- zero: binCnt, overflow cursor ----------------
__global__ void k_zero(int* __restrict__ binCnt, int* __restrict__ ocur) {
    int i = blockIdx.x * blockDim.x + threadIdx.x;
    if (i < NBIN) binCnt[i] = 0;
    if (i == 0) *ocur = 0;
}

// ---------------- partition: block-local counting sort, 4 blocks/CU ----------
// LDS ~40.1KB -> 4 blocks/CU (16 waves). sbinm written inline during staging
// (old serial phase-4 deleted). shist doubles as local exclusive offsets.
__global__ __launch_bounds__(256, 4) void k_part(
        const int* __restrict__ row, const int* __restrict__ col,
        const float* __restrict__ ew, int* __restrict__ binCnt,
        int2* __restrict__ binned, int* __restrict__ ocur, int* __restrict__ olist) {
    __shared__ int2 sed[PEPB];                 // 24576 B staged edges (grouped)
    __shared__ unsigned short sbinm[PEPB];     //  6144 B staged-pos -> bin
    __shared__ int shist[NBIN];                // counts -> local excl offsets
    __shared__ int sbase[NBIN];                // global run base
    __shared__ int scur[NBIN];                 // scan scratch, then cursors
    const int tid = threadIdx.x;
    const int e0 = blockIdx.x * PEPB;
    const int ne = min(PEPB, N_EDGES - e0);

    for (int i = tid; i < NBIN; i += 256) shist[i] = 0;
    __syncthreads();
    // phase 1: histogram
    for (int i = tid; i < ne; i += 256) atomicAdd(&shist[col[e0 + i] >> 7], 1);
    __syncthreads();
    // phase 2: block scan (4 bins/thread, scratch in scur) + run allocation
    int l[4];
    int s = 0;
#pragma unroll
    for (int k = 0; k < 4; ++k) {
        int b = tid * 4 + k;
        l[k] = (b < NBIN) ? shist[b] : 0;
        s += l[k];
    }
    scur[tid] = s;
    __syncthreads();
    for (int d = 1; d < 256; d <<= 1) {
        int t = (tid >= d) ? scur[tid - d] : 0;
        __syncthreads();
        scur[tid] += t;
        __syncthreads();
    }
    int ex = scur[tid] - s;
    __syncthreads();  // scratch reads done before scur reused as cursors
#pragma unroll
    for (int k = 0; k < 4; ++k) {
        int b = tid * 4 + k;
        if (b < NBIN) {
            shist[b] = ex;                     // local exclusive offset
            scur[b] = ex;                      // cursor
            if (l[k] > 0) sbase[b] = atomicAdd(&binCnt[b], l[k]);
            ex += l[k];
        }
    }
    __syncthreads();
    // phase 3: stage edges grouped by bin; bin map inline; overflow -> olist
    for (int i = tid; i < ne; i += 256) {
        int e = e0 + i;
        int c = col[e];
        int b = c >> 7;
        int p = atomicAdd(&scur[b], 1);        // staged position
        int slot = sbase[b] + (p - shist[b]);
        if (slot < CAPB) {
            sed[p] = make_int2(((c & (NPB - 1)) << 17) | row[e], __float_as_int(ew[e]));
            sbinm[p] = (unsigned short)b;
        } else {
            sbinm[p] = 0xFFFFu;                // hole
            int q = atomicAdd(ocur, 1);
            if (q < OCAP) olist[q] = e;
        }
    }
    __syncthreads();
    // phase 4: run-coalesced write-out
    for (int i = tid; i < ne; i += 256) {
        int b = sbinm[i];
        if (b == 0xFFFF) continue;
        int slot = sbase[b] + (i - shist[b]);
        binned[(size_t)b * CAPB + slot] = sed[i];
    }
}

// ---------------- per-bin: group by (node, src-tile), deg, off2 ----------------
__global__ __launch_bounds__(256) void k_build(
        const int* __restrict__ binCnt, int2* __restrict__ binned,
        float* __restrict__ deg, int2* __restrict__ off2) {
    __shared__ int2 se[CAPB];                      // 36864 B
    __shared__ int scnt[NSK], scur[NSK];           // 2 x 4096 B
    __shared__ float sdeg[NPB];
    __shared__ int spart[256];
    const int bin = blockIdx.x, tid = threadIdx.x;
    const int n = min(binCnt[bin], CAPB);
    const size_t base = (size_t)bin * CAPB;

    for (int i = tid; i < NSK; i += 256) scnt[i] = 0;
    for (int i = tid; i < NPB; i += 256) sdeg[i] = 0.f;
    __syncthreads();
    for (int i = tid; i < n; i += 256) {
        int2 v = binned[base + i];
        se[i] = v;
        int lc = v.x >> 17, src = v.x & 0x1FFFF;
        atomicAdd(&scnt[lc * 8 + (src >> 14)], 1);
        atomicAdd(&sdeg[lc], __int_as_float(v.y));
    }
    __syncthreads();
    int l0 = scnt[tid * 4], l1 = scnt[tid * 4 + 1],
        l2 = scnt[tid * 4 + 2], l3 = scnt[tid * 4 + 3];
    int s = l0 + l1 + l2 + l3;
    spart[tid] = s;
    __syncthreads();
    for (int d = 1; d < 256; d <<= 1) {
        int t = (tid >= d) ? spart[tid - d] : 0;
        __syncthreads();
        spart[tid] += t;
        __syncthreads();
    }
    int ex = spart[tid] - s;
    scnt[tid * 4] = ex;
    scnt[tid * 4 + 1] = ex + l0;
    scnt[tid * 4 + 2] = ex + l0 + l1;
    scnt[tid * 4 + 3] = ex + l0 + l1 + l2;
    __syncthreads();
    for (int i = tid; i < NSK; i += 256) scur[i] = scnt[i];
    __syncthreads();
    if (tid < NPB) {
        int node = bin * NPB + tid;
        if (node < N_NODES) {
            int st = scnt[tid * 8];
            int en = (tid == NPB - 1) ? n : scnt[(tid + 1) * 8];
            off2[node] = make_int2((int)base + st, en - st);
            deg[node] = sdeg[tid] + 1.0f;  // + self loop
        }
    }
    __syncthreads();
    for (int i = tid; i < n; i += 256) {
        int2 v = se[i];
        int lc = v.x >> 17, src = v.x & 0x1FFFF;
        int s2 = atomicAdd(&scur[lc * 8 + (src >> 14)], 1);  // LDS atomic
        binned[base + s2] = make_int2(src, v.y);             // {src, ew}
    }
}

__global__ void k_degover(const int* __restrict__ ocur, const int* __restrict__ olist,
                          const int* __restrict__ col, const float* __restrict__ ew,
                          float* __restrict__ deg) {
    int p = blockIdx.x * blockDim.x + threadIdx.x;
    int n = min(*ocur, OCAP);
    if (p < n) { int e = olist[p]; unsafeAtomicAdd(&deg[col[e]], ew[e]); }
}

__global__ void k_dis(float* __restrict__ deg) {
    int i = blockIdx.x * blockDim.x + threadIdx.x;
    if (i < N_NODES) {
        float d = deg[i];
        deg[i] = (d > 0.0f) ? rsqrtf(d) : 0.0f;
    }
}

// ---------------- fold dis[src] into csr weights in-place ----------------
__global__ void k_wnorm(const int* __restrict__ binCnt, int2* __restrict__ csr,
                        const float* __restrict__ dis) {
    int bin = blockIdx.x;
    int n = min(binCnt[bin], CAPB);
    size_t base = (size_t)bin * CAPB;
    for (int i = threadIdx.x; i < n; i += 256) {
        int2 v = csr[base + i];
        float w = __int_as_float(v.y) * dis[v.x];
        csr[base + i] = make_int2(v.x, __float_as_int(w));
    }
}

// ---------------- layer 1 GEMM: h = x @ W1^T (unchanged) ----------------
__global__ __launch_bounds__(256) void k_gemm1(
        const float* __restrict__ x, const float* __restrict__ W1,
        float* __restrict__ h) {
    __shared__ float sx[GR][GS];
    __shared__ float sw[HIDDEN][GS];

    const int tid = threadIdx.x;
    const size_t base = (size_t)blockIdx.x * GR;
    const float4* x4 = (const float4*)x;
    const float4* w4 = (const float4*)W1;

    const int r0 = tid >> 3;
    const int c0 = tid & 7;
    float acc[4][4] = {};

#pragma unroll
    for (int p = 0; p < 4; ++p) {
        for (int i = tid; i < GR * 16; i += 256) {
            int r = i >> 4, kq = i & 15;
            float4 v = make_float4(0.f, 0.f, 0.f, 0.f);
            if (base + r < N_NODES) v = x4[(base + r) * 64 + p * 16 + kq];
            *(float4*)&sx[r][kq * 4] = v;
        }
        for (int i = tid; i < HIDDEN * 16; i += 256) {
            int f = i >> 4, kq = i & 15;
            *(float4*)&sw[f][kq * 4] = w4[f * 64 + p * 16 + kq];
        }
        __syncthreads();

#pragma unroll 4
        for (int kq = 0; kq < 16; ++kq) {
            float4 xa[4], wv[4];
#pragma unroll
            for (int m = 0; m < 4; ++m) xa[m] = *(const float4*)&sx[r0 + 32 * m][kq * 4];
#pragma unroll
            for (int j = 0; j < 4; ++j) wv[j] = *(const float4*)&sw[c0 + 8 * j][kq * 4];
#pragma unroll
            for (int m = 0; m < 4; ++m)
#pragma unroll
                for (int j = 0; j < 4; ++j)
                    acc[m][j] += xa[m].x * wv[j].x + xa[m].y * wv[j].y +
                                 xa[m].z * wv[j].z + xa[m].w * wv[j].w;
        }
        __syncthreads();
    }

#pragma unroll
    for (int m = 0; m < 4; ++m) {
        size_t r = base + r0 + 32 * m;
        if (r < N_NODES) {
#pragma unroll
            for (int j = 0; j < 4; ++j) h[r * HIDDEN + c0 + 8 * j] = acc[m][j];
        }
    }
}

// ---- layer 1 gather: LDS-staged csr window (unchanged) ----
__global__ __launch_bounds__(256) void k_gather1(
        const int2* __restrict__ off2, const int2* __restrict__ csr,
        const float* __restrict__ h, const float* __restrict__ dis,
        const float* __restrict__ b1, float* __restrict__ out1) {
    __shared__ int2 sc[G1CAP];
    __shared__ int s_start, s_n;
    const int tid = threadIdx.x;
    const int node0 = blockIdx.x * G1N;
    if (tid == 0) {
        int2 a = off2[node0];
        int2 b = off2[node0 + G1N - 1];
        s_start = a.x;
        s_n = b.x + b.y - a.x;
    }
    __syncthreads();
    const int start = s_start, n = s_n;
    const bool fit = (n <= G1CAP);
    if (fit) for (int i = tid; i < n; i += 256) sc[i] = csr[start + i];
    __syncthreads();

    const int node = node0 + (tid >> 3);
    const int og = tid & 7;
    float d = dis[node];
    float d2 = d * d;
    float4 self = *(const float4*)(h + (size_t)node * HIDDEN + og * 4);
    float4 bv = *(const float4*)(b1 + og * 4);
    float4 acc = make_float4(0.f, 0.f, 0.f, 0.f);

    int2 o = off2[node];
    for (int j = 0; j < o.y; ++j) {
        int2 v = fit ? sc[o.x - start + j] : csr[o.x + j];
        float w = __int_as_float(v.y);
        const float4 hv = *(const float4*)(h + (size_t)v.x * HIDDEN + og * 4);
        acc.x += hv.x * w; acc.y += hv.y * w; acc.z += hv.z * w; acc.w += hv.w * w;
    }
    *(float4*)(out1 + (size_t)node * HIDDEN + og * 4) =
        make_float4(acc.x * d + self.x * d2 + bv.x, acc.y * d + self.y * d2 + bv.y,
                    acc.z * d + self.z * d2 + bv.z, acc.w * d + self.w * d2 + bv.w);
}

__global__ void k_over1(const int* __restrict__ ocur, const int* __restrict__ olist,
                        const int* __restrict__ row, const int* __restrict__ col,
                        const float* __restrict__ ew, const float* __restrict__ dis,
                        const float* __restrict__ h, float* __restrict__ out1) {
    int p = blockIdx.x * blockDim.x + threadIdx.x;
    int n = min(*ocur, OCAP);
    if (p < n) {
        int e = olist[p];
        int r = row[e], c = col[e];
        float w = dis[r] * ew[e] * dis[c];
        for (int f = 0; f < HIDDEN; ++f)
            unsafeAtomicAdd(&out1[(size_t)c * HIDDEN + f], h[(size_t)r * HIDDEN + f] * w);
    }
}

// ---------------- layer 2 GEMM: h2 = relu(out1) @ W2^T ----------------
__global__ void k_gemm2(const float* __restrict__ out1, const float* __restrict__ W2,
                        float* __restrict__ h2) {
    int t = blockIdx.x * blockDim.x + threadIdx.x;
    int i = t >> 4;
    if (i >= N_NODES) return;
    int f = t & 15;
    const float* r = out1 + (size_t)i * HIDDEN;
    const float* w = W2 + f * HIDDEN;
    float acc = 0.f;
#pragma unroll
    for (int k = 0; k < HIDDEN; ++k) acc += fmaxf(r[k], 0.f) * w[k];
    h2[(size_t)i * EMBED + f] = acc;
}

// ---- layer 2 gather: LDS-staged csr window (unchanged) ----
__global__ __launch_bounds__(256) void k_gather2(
        const int2* __restrict__ off2, const int2* __restrict__ csr,
        const float* __restrict__ h2, const float* __restrict__ dis,
        const float* __restrict__ b2, float* __restrict__ out) {
    __shared__ int2 sc[G2CAP];
    __shared__ int s_start, s_n;
    const int tid = threadIdx.x;
    const int node0 = blockIdx.x * G2N;
    const int lastn = min(node0 + G2N, N_NODES) - 1;
    if (tid == 0) {
        int2 a = off2[node0];
        int2 b = off2[lastn];
        s_start = a.x;
        s_n = b.x + b.y - a.x;
    }
    __syncthreads();
    const int start = s_start, n = s_n;
    const bool fit = (n <= G2CAP);
    if (fit) for (int i = tid; i < n; i += 256) sc[i] = csr[start + i];
    __syncthreads();

    const int node = node0 + (tid >> 2);
    const int og = tid & 3;
    if (node >= N_NODES) return;
    float d = dis[node];
    float d2 = d * d;
    float4 self = *(const float4*)(h2 + (size_t)node * EMBED + og * 4);
    float4 bv = *(const float4*)(b2 + og * 4);
    float4 acc = make_float4(0.f, 0.f, 0.f, 0.f);

    int2 o = off2[node];
    for (int j = 0; j < o.y; ++j) {
        int2 v = fit ? sc[o.x - start + j] : csr[o.x + j];
        float w = __int_as_float(v.y);
        const float4 hv = *(const float4*)(h2 + (size_t)v.x * EMBED + og * 4);
        acc.x += hv.x * w; acc.y += hv.y * w; acc.z += hv.z * w; acc.w += hv.w * w;
    }
    *(float4*)(out + (size_t)node * EMBED + og * 4) =
        make_float4(acc.x * d + self.x * d2 + bv.x, acc.y * d + self.y * d2 + bv.y,
                    acc.z * d + self.z * d2 + bv.z, acc.w * d + self.w * d2 + bv.w);
}

__global__ void k_over2(const int* __restrict__ ocur, const int* __restrict__ olist,
                        const int* __restrict__ row, const int* __restrict__ col,
                        const float* __restrict__ ew, const float* __restrict__ dis,
                        const float* __restrict__ h2, float* __restrict__ out) {
    int p = blockIdx.x * blockDim.x + threadIdx.x;
    int n = min(*ocur, OCAP);
    if (p < n) {
        int e = olist[p];
        int r = row[e], c = col[e];
        float w = dis[r] * ew[e] * dis[c];
        for (int f = 0; f < EMBED; ++f)
            unsafeAtomicAdd(&out[(size_t)c * EMBED + f], h2[(size_t)r * EMBED + f] * w);
    }
}

extern "C" void kernel_launch(void* const* d_in, const int* in_sizes, int n_in,
                              void* d_out, int out_size, void* d_ws, size_t ws_size,
                              hipStream_t stream) {
    const float* x  = (const float*)d_in[0];
    const int*   ei = (const int*)d_in[1];  // [2, E] int32
    const float* ew = (const float*)d_in[2];
    const float* W1 = (const float*)d_in[3];
    const float* b1 = (const float*)d_in[4];
    const float* W2 = (const float*)d_in[5];
    const float* b2 = (const float*)d_in[6];
    float* out = (float*)d_out;

    const int* row = ei;            // source
    const int* col = ei + N_EDGES;  // target

    int2*  off2   = (int2*)d_ws;
    int2*  binned = off2 + N_NODES;
    float* deg    = (float*)(binned + (size_t)NBIN * CAPB);
    int*   binCnt = (int*)(deg + N_NODES);
    int*   ocur   = binCnt + NBIN;
    int*   olist  = ocur + 2;
    size_t off_i  = (size_t)(olist + OCAP - (int*)d_ws);
    off_i = (off_i + 3) & ~(size_t)3;            // 16B align
    float* h    = (float*)d_ws + off_i;
    float* out1 = h + (size_t)N_NODES * HIDDEN;
    float* h2   = h;  // alias: h dead after k_gather1

    const int B = 256;
    const int gN = (N_NODES + B - 1) / B;
    const int gO = (OCAP + B - 1) / B;

    k_zero<<<(NBIN + B - 1) / B, B, 0, stream>>>(binCnt, ocur);
    k_part<<<PBLK, B, 0, stream>>>(row, col, ew, binCnt, binned, ocur, olist);
    k_build<<<NBIN, B, 0, stream>>>(binCnt, binned, deg, off2);
    k_degover<<<gO, B, 0, stream>>>(ocur, olist, col, ew, deg);
    k_dis<<<gN, B, 0, stream>>>(deg);
    k_wnorm<<<NBIN, B, 0, stream>>>(binCnt, binned, deg);
    k_gemm1<<<(N_NODES + GR - 1) / GR, B, 0, stream>>>(x, W1, h);
    k_gather1<<<N_NODES / G1N, B, 0, stream>>>(off2, binned, h, deg, b1, out1);
    k_over1<<<gO, B, 0, stream>>>(ocur, olist, row, col, ew, deg, h, out1);
    k_gemm2<<<(N_NODES * 16 + B - 1) / B, B, 0, stream>>>(out1, W2, h2);
    k_gather2<<<(N_NODES + G2N - 1) / G2N, B, 0, stream>>>(off2, binned, h2, deg, b2, out);
    k_over2<<<gO, B, 0, stream>>>(ocur, olist, row, col, ew, deg, h2, out);
}

// Round 16
// 353.139 us; speedup vs baseline: 1.0759x; 1.0759x over previous
//
#include <hip/hip_runtime.h>
#include <hip/hip_bf16.h>

#define N_NODES 100000
#define N_EDGES 3200000
#define FEAT 256
#define HIDDEN 32
#define EMBED 16
#define NPB 128                                // nodes per bin
#define NBIN ((N_NODES + NPB - 1) / NPB)       // 782
#define CAPB 4608                              // bin capacity (mean 4096 + 8 sigma)
#define OCAP 8192                              // overflow list capacity
#define GR 128                                 // gemm1 tile rows
#define GS 68                                  // LDS row stride (floats)
#define G1N 32                                 // nodes per gather1 block
#define G1CAP 2048                             // LDS entries
#define G2N 64                                 // nodes per gather2 block
#define G2CAP 3072                             // LDS entries
#define PEPB 3072                              // edges per partition block
#define PBLK ((N_EDGES + PEPB - 1) / PEPB)     // 1042
#define NSK (NPB * 8)                          // sub-keys: node x 8 src-tiles
#define BCS 16                                 // binCnt stride (ints): 1 counter/64B line

// ---------------- zero: binCnt (padded), overflow cursor ----------------
__global__ void k_zero(int* __restrict__ binCnt, int* __restrict__ ocur) {
    int i = blockIdx.x * blockDim.x + threadIdx.x;
    if (i < NBIN) binCnt[i * BCS] = 0;
    if (i == 0) *ocur = 0;
}

// ---------------- partition: block-local counting sort, 4 blocks/CU ----------
// binCnt padded to 1 counter per 64B line: run-allocation atomics to different
// bins no longer serialize on shared cache lines (R15: 16 counters/line x 1042
// blocks = 16.7K serialized ops/line ~ 117us; padded: 1042 ops/line, parallel).
__global__ __launch_bounds__(256, 4) void k_part(
        const int* __restrict__ row, const int* __restrict__ col,
        const float* __restrict__ ew, int* __restrict__ binCnt,
        int2* __restrict__ binned, int* __restrict__ ocur, int* __restrict__ olist) {
    __shared__ int2 sed[PEPB];                 // 24576 B staged edges (grouped)
    __shared__ unsigned short sbinm[PEPB];     //  6144 B staged-pos -> bin
    __shared__ int shist[NBIN];                // counts -> local excl offsets
    __shared__ int sbase[NBIN];                // global run base
    __shared__ int scur[NBIN];                 // scan scratch, then cursors
    const int tid = threadIdx.x;
    const int e0 = blockIdx.x * PEPB;
    const int ne = min(PEPB, N_EDGES - e0);

    for (int i = tid; i < NBIN; i += 256) shist[i] = 0;
    __syncthreads();
    // phase 1: histogram
    for (int i = tid; i < ne; i += 256) atomicAdd(&shist[col[e0 + i] >> 7], 1);
    __syncthreads();
    // phase 2: block scan (4 bins/thread, scratch in scur) + run allocation
    int l[4];
    int s = 0;
#pragma unroll
    for (int k = 0; k < 4; ++k) {
        int b = tid * 4 + k;
        l[k] = (b < NBIN) ? shist[b] : 0;
        s += l[k];
    }
    scur[tid] = s;
    __syncthreads();
    for (int d = 1; d < 256; d <<= 1) {
        int t = (tid >= d) ? scur[tid - d] : 0;
        __syncthreads();
        scur[tid] += t;
        __syncthreads();
    }
    int ex = scur[tid] - s;
    __syncthreads();  // scratch reads done before scur reused as cursors
#pragma unroll
    for (int k = 0; k < 4; ++k) {
        int b = tid * 4 + k;
        if (b < NBIN) {
            shist[b] = ex;                     // local exclusive offset
            scur[b] = ex;                      // cursor
            if (l[k] > 0) sbase[b] = atomicAdd(&binCnt[b * BCS], l[k]);
            ex += l[k];
        }
    }
    __syncthreads();
    // phase 3: stage edges grouped by bin; bin map inline; overflow -> olist
    for (int i = tid; i < ne; i += 256) {
        int e = e0 + i;
        int c = col[e];
        int b = c >> 7;
        int p = atomicAdd(&scur[b], 1);        // staged position
        int slot = sbase[b] + (p - shist[b]);
        if (slot < CAPB) {
            sed[p] = make_int2(((c & (NPB - 1)) << 17) | row[e], __float_as_int(ew[e]));
            sbinm[p] = (unsigned short)b;
        } else {
            sbinm[p] = 0xFFFFu;                // hole
            int q = atomicAdd(ocur, 1);
            if (q < OCAP) olist[q] = e;
        }
    }
    __syncthreads();
    // phase 4: run-coalesced write-out
    for (int i = tid; i < ne; i += 256) {
        int b = sbinm[i];
        if (b == 0xFFFF) continue;
        int slot = sbase[b] + (i - shist[b]);
        binned[(size_t)b * CAPB + slot] = sed[i];
    }
}

// ---------------- per-bin: group by (node, src-tile), deg, off2 ----------------
__global__ __launch_bounds__(256) void k_build(
        const int* __restrict__ binCnt, int2* __restrict__ binned,
        float* __restrict__ deg, int2* __restrict__ off2) {
    __shared__ int2 se[CAPB];                      // 36864 B
    __shared__ int scnt[NSK], scur[NSK];           // 2 x 4096 B
    __shared__ float sdeg[NPB];
    __shared__ int spart[256];
    const int bin = blockIdx.x, tid = threadIdx.x;
    const int n = min(binCnt[bin * BCS], CAPB);
    const size_t base = (size_t)bin * CAPB;

    for (int i = tid; i < NSK; i += 256) scnt[i] = 0;
    for (int i = tid; i < NPB; i += 256) sdeg[i] = 0.f;
    __syncthreads();
    for (int i = tid; i < n; i += 256) {
        int2 v = binned[base + i];
        se[i] = v;
        int lc = v.x >> 17, src = v.x & 0x1FFFF;
        atomicAdd(&scnt[lc * 8 + (src >> 14)], 1);
        atomicAdd(&sdeg[lc], __int_as_float(v.y));
    }
    __syncthreads();
    int l0 = scnt[tid * 4], l1 = scnt[tid * 4 + 1],
        l2 = scnt[tid * 4 + 2], l3 = scnt[tid * 4 + 3];
    int s = l0 + l1 + l2 + l3;
    spart[tid] = s;
    __syncthreads();
    for (int d = 1; d < 256; d <<= 1) {
        int t = (tid >= d) ? spart[tid - d] : 0;
        __syncthreads();
        spart[tid] += t;
        __syncthreads();
    }
    int ex = spart[tid] - s;
    scnt[tid * 4] = ex;
    scnt[tid * 4 + 1] = ex + l0;
    scnt[tid * 4 + 2] = ex + l0 + l1;
    scnt[tid * 4 + 3] = ex + l0 + l1 + l2;
    __syncthreads();
    for (int i = tid; i < NSK; i += 256) scur[i] = scnt[i];
    __syncthreads();
    if (tid < NPB) {
        int node = bin * NPB + tid;
        if (node < N_NODES) {
            int st = scnt[tid * 8];
            int en = (tid == NPB - 1) ? n : scnt[(tid + 1) * 8];
            off2[node] = make_int2((int)base + st, en - st);
            deg[node] = sdeg[tid] + 1.0f;  // + self loop
        }
    }
    __syncthreads();
    for (int i = tid; i < n; i += 256) {
        int2 v = se[i];
        int lc = v.x >> 17, src = v.x & 0x1FFFF;
        int s2 = atomicAdd(&scur[lc * 8 + (src >> 14)], 1);  // LDS atomic
        binned[base + s2] = make_int2(src, v.y);             // {src, ew}
    }
}

__global__ void k_degover(const int* __restrict__ ocur, const int* __restrict__ olist,
                          const int* __restrict__ col, const float* __restrict__ ew,
                          float* __restrict__ deg) {
    int p = blockIdx.x * blockDim.x + threadIdx.x;
    int n = min(*ocur, OCAP);
    if (p < n) { int e = olist[p]; unsafeAtomicAdd(&deg[col[e]], ew[e]); }
}

__global__ void k_dis(float* __restrict__ deg) {
    int i = blockIdx.x * blockDim.x + threadIdx.x;
    if (i < N_NODES) {
        float d = deg[i];
        deg[i] = (d > 0.0f) ? rsqrtf(d) : 0.0f;
    }
}

// ---------------- fold dis[src] into csr weights in-place ----------------
__global__ void k_wnorm(const int* __restrict__ binCnt, int2* __restrict__ csr,
                        const float* __restrict__ dis) {
    int bin = blockIdx.x;
    int n = min(binCnt[bin * BCS], CAPB);
    size_t base = (size_t)bin * CAPB;
    for (int i = threadIdx.x; i < n; i += 256) {
        int2 v = csr[base + i];
        float w = __int_as_float(v.y) * dis[v.x];
        csr[base + i] = make_int2(v.x, __float_as_int(w));
    }
}

// ---------------- layer 1 GEMM: h = x @ W1^T (unchanged) ----------------
__global__ __launch_bounds__(256) void k_gemm1(
        const float* __restrict__ x, const float* __restrict__ W1,
        float* __restrict__ h) {
    __shared__ float sx[GR][GS];
    __shared__ float sw[HIDDEN][GS];

    const int tid = threadIdx.x;
    const size_t base = (size_t)blockIdx.x * GR;
    const float4* x4 = (const float4*)x;
    const float4* w4 = (const float4*)W1;

    const int r0 = tid >> 3;
    const int c0 = tid & 7;
    float acc[4][4] = {};

#pragma unroll
    for (int p = 0; p < 4; ++p) {
        for (int i = tid; i < GR * 16; i += 256) {
            int r = i >> 4, kq = i & 15;
            float4 v = make_float4(0.f, 0.f, 0.f, 0.f);
            if (base + r < N_NODES) v = x4[(base + r) * 64 + p * 16 + kq];
            *(float4*)&sx[r][kq * 4] = v;
        }
        for (int i = tid; i < HIDDEN * 16; i += 256) {
            int f = i >> 4, kq = i & 15;
            *(float4*)&sw[f][kq * 4] = w4[f * 64 + p * 16 + kq];
        }
        __syncthreads();

#pragma unroll 4
        for (int kq = 0; kq < 16; ++kq) {
            float4 xa[4], wv[4];
#pragma unroll
            for (int m = 0; m < 4; ++m) xa[m] = *(const float4*)&sx[r0 + 32 * m][kq * 4];
#pragma unroll
            for (int j = 0; j < 4; ++j) wv[j] = *(const float4*)&sw[c0 + 8 * j][kq * 4];
#pragma unroll
            for (int m = 0; m < 4; ++m)
#pragma unroll
                for (int j = 0; j < 4; ++j)
                    acc[m][j] += xa[m].x * wv[j].x + xa[m].y * wv[j].y +
                                 xa[m].z * wv[j].z + xa[m].w * wv[j].w;
        }
        __syncthreads();
    }

#pragma unroll
    for (int m = 0; m < 4; ++m) {
        size_t r = base + r0 + 32 * m;
        if (r < N_NODES) {
#pragma unroll
            for (int j = 0; j < 4; ++j) h[r * HIDDEN + c0 + 8 * j] = acc[m][j];
        }
    }
}

// ---- layer 1 gather: LDS-staged csr window (unchanged) ----
__global__ __launch_bounds__(256) void k_gather1(
        const int2* __restrict__ off2, const int2* __restrict__ csr,
        const float* __restrict__ h, const float* __restrict__ dis,
        const float* __restrict__ b1, float* __restrict__ out1) {
    __shared__ int2 sc[G1CAP];
    __shared__ int s_start, s_n;
    const int tid = threadIdx.x;
    const int node0 = blockIdx.x * G1N;
    if (tid == 0) {
        int2 a = off2[node0];
        int2 b = off2[node0 + G1N - 1];
        s_start = a.x;
        s_n = b.x + b.y - a.x;
    }
    __syncthreads();
    const int start = s_start, n = s_n;
    const bool fit = (n <= G1CAP);
    if (fit) for (int i = tid; i < n; i += 256) sc[i] = csr[start + i];
    __syncthreads();

    const int node = node0 + (tid >> 3);
    const int og = tid & 7;
    float d = dis[node];
    float d2 = d * d;
    float4 self = *(const float4*)(h + (size_t)node * HIDDEN + og * 4);
    float4 bv = *(const float4*)(b1 + og * 4);
    float4 acc = make_float4(0.f, 0.f, 0.f, 0.f);

    int2 o = off2[node];
    for (int j = 0; j < o.y; ++j) {
        int2 v = fit ? sc[o.x - start + j] : csr[o.x + j];
        float w = __int_as_float(v.y);
        const float4 hv = *(const float4*)(h + (size_t)v.x * HIDDEN + og * 4);
        acc.x += hv.x * w; acc.y += hv.y * w; acc.z += hv.z * w; acc.w += hv.w * w;
    }
    *(float4*)(out1 + (size_t)node * HIDDEN + og * 4) =
        make_float4(acc.x * d + self.x * d2 + bv.x, acc.y * d + self.y * d2 + bv.y,
                    acc.z * d + self.z * d2 + bv.z, acc.w * d + self.w * d2 + bv.w);
}

__global__ void k_over1(const int* __restrict__ ocur, const int* __restrict__ olist,
                        const int* __restrict__ row, const int* __restrict__ col,
                        const float* __restrict__ ew, const float* __restrict__ dis,
                        const float* __restrict__ h, float* __restrict__ out1) {
    int p = blockIdx.x * blockDim.x + threadIdx.x;
    int n = min(*ocur, OCAP);
    if (p < n) {
        int e = olist[p];
        int r = row[e], c = col[e];
        float w = dis[r] * ew[e] * dis[c];
        for (int f = 0; f < HIDDEN; ++f)
            unsafeAtomicAdd(&out1[(size_t)c * HIDDEN + f], h[(size_t)r * HIDDEN + f] * w);
    }
}

// ---------------- layer 2 GEMM: h2 = relu(out1) @ W2^T ----------------
__global__ void k_gemm2(const float* __restrict__ out1, const float* __restrict__ W2,
                        float* __restrict__ h2) {
    int t = blockIdx.x * blockDim.x + threadIdx.x;
    int i = t >> 4;
    if (i >= N_NODES) return;
    int f = t & 15;
    const float* r = out1 + (size_t)i * HIDDEN;
    const float* w = W2 + f * HIDDEN;
    float acc = 0.f;
#pragma unroll
    for (int k = 0; k < HIDDEN; ++k) acc += fmaxf(r[k], 0.f) * w[k];
    h2[(size_t)i * EMBED + f] = acc;
}

// ---- layer 2 gather: LDS-staged csr window (unchanged) ----
__global__ __launch_bounds__(256) void k_gather2(
        const int2* __restrict__ off2, const int2* __restrict__ csr,
        const float* __restrict__ h2, const float* __restrict__ dis,
        const float* __restrict__ b2, float* __restrict__ out) {
    __shared__ int2 sc[G2CAP];
    __shared__ int s_start, s_n;
    const int tid = threadIdx.x;
    const int node0 = blockIdx.x * G2N;
    const int lastn = min(node0 + G2N, N_NODES) - 1;
    if (tid == 0) {
        int2 a = off2[node0];
        int2 b = off2[lastn];
        s_start = a.x;
        s_n = b.x + b.y - a.x;
    }
    __syncthreads();
    const int start = s_start, n = s_n;
    const bool fit = (n <= G2CAP);
    if (fit) for (int i = tid; i < n; i += 256) sc[i] = csr[start + i];
    __syncthreads();

    const int node = node0 + (tid >> 2);
    const int og = tid & 3;
    if (node >= N_NODES) return;
    float d = dis[node];
    float d2 = d * d;
    float4 self = *(const float4*)(h2 + (size_t)node * EMBED + og * 4);
    float4 bv = *(const float4*)(b2 + og * 4);
    float4 acc = make_float4(0.f, 0.f, 0.f, 0.f);

    int2 o = off2[node];
    for (int j = 0; j < o.y; ++j) {
        int2 v = fit ? sc[o.x - start + j] : csr[o.x + j];
        float w = __int_as_float(v.y);
        const float4 hv = *(const float4*)(h2 + (size_t)v.x * EMBED + og * 4);
        acc.x += hv.x * w; acc.y += hv.y * w; acc.z += hv.z * w; acc.w += hv.w * w;
    }
    *(float4*)(out + (size_t)node * EMBED + og * 4) =
        make_float4(acc.x * d + self.x * d2 + bv.x, acc.y * d + self.y * d2 + bv.y,
                    acc.z * d + self.z * d2 + bv.z, acc.w * d + self.w * d2 + bv.w);
}

__global__ void k_over2(const int* __restrict__ ocur, const int* __restrict__ olist,
                        const int* __restrict__ row, const int* __restrict__ col,
                        const float* __restrict__ ew, const float* __restrict__ dis,
                        const float* __restrict__ h2, float* __restrict__ out) {
    int p = blockIdx.x * blockDim.x + threadIdx.x;
    int n = min(*ocur, OCAP);
    if (p < n) {
        int e = olist[p];
        int r = row[e], c = col[e];
        float w = dis[r] * ew[e] * dis[c];
        for (int f = 0; f < EMBED; ++f)
            unsafeAtomicAdd(&out[(size_t)c * EMBED + f], h2[(size_t)r * EMBED + f] * w);
    }
}

extern "C" void kernel_launch(void* const* d_in, const int* in_sizes, int n_in,
                              void* d_out, int out_size, void* d_ws, size_t ws_size,
                              hipStream_t stream) {
    const float* x  = (const float*)d_in[0];
    const int*   ei = (const int*)d_in[1];  // [2, E] int32
    const float* ew = (const float*)d_in[2];
    const float* W1 = (const float*)d_in[3];
    const float* b1 = (const float*)d_in[4];
    const float* W2 = (const float*)d_in[5];
    const float* b2 = (const float*)d_in[6];
    float* out = (float*)d_out;

    const int* row = ei;            // source
    const int* col = ei + N_EDGES;  // target

    int2*  off2   = (int2*)d_ws;
    int2*  binned = off2 + N_NODES;
    float* deg    = (float*)(binned + (size_t)NBIN * CAPB);
    int*   binCnt = (int*)(deg + N_NODES);       // NBIN*BCS ints (padded)
    int*   ocur   = binCnt + NBIN * BCS;
    int*   olist  = ocur + 2;
    size_t off_i  = (size_t)(olist + OCAP - (int*)d_ws);
    off_i = (off_i + 3) & ~(size_t)3;            // 16B align
    float* h    = (float*)d_ws + off_i;
    float* out1 = h + (size_t)N_NODES * HIDDEN;
    float* h2   = h;  // alias: h dead after k_gather1

    const int B = 256;
    const int gN = (N_NODES + B - 1) / B;
    const int gO = (OCAP + B - 1) / B;

    k_zero<<<(NBIN + B - 1) / B, B, 0, stream>>>(binCnt, ocur);
    k_part<<<PBLK, B, 0, stream>>>(row, col, ew, binCnt, binned, ocur, olist);
    k_build<<<NBIN, B, 0, stream>>>(binCnt, binned, deg, off2);
    k_degover<<<gO, B, 0, stream>>>(ocur, olist, col, ew, deg);
    k_dis<<<gN, B, 0, stream>>>(deg);
    k_wnorm<<<NBIN, B, 0, stream>>>(binCnt, binned, deg);
    k_gemm1<<<(N_NODES + GR - 1) / GR, B, 0, stream>>>(x, W1, h);
    k_gather1<<<N_NODES / G1N, B, 0, stream>>>(off2, binned, h, deg, b1, out1);
    k_over1<<<gO, B, 0, stream>>>(ocur, olist, row, col, ew, deg, h, out1);
    k_gemm2<<<(N_NODES * 16 + B - 1) / B, B, 0, stream>>>(out1, W2, h2);
    k_gather2<<<(N_NODES + G2N - 1) / G2N, B, 0, stream>>>(off2, binned, h2, deg, b2, out);
    k_over2<<<gO, B, 0, stream>>>(ocur, olist, row, col, ew, deg, h2, out);
}

// Round 17
// 319.975 us; speedup vs baseline: 1.1874x; 1.1036x over previous
//
#include <hip/hip_runtime.h>
#include <hip/hip_bf16.h>

#define N_NODES 100000
#define N_EDGES 3200000
#define FEAT 256
#define HIDDEN 32
#define EMBED 16
#define NPB 128                                // nodes per bin
#define NBIN ((N_NODES + NPB - 1) / NPB)       // 782
#define CAPB 4608                              // bin capacity (mean 4096 + 8 sigma)
#define OCAP 8192                              // overflow list capacity
#define GR 128                                 // gemm1 tile rows
#define GS 68                                  // LDS row stride (floats)
#define G1N 32                                 // nodes per gather1 block
#define G1CAP 2048                             // LDS entries
#define G2N 64                                 // nodes per gather2 block
#define G2CAP 3072                             // LDS entries
#define PEPB 3072                              // edges per partition block
#define PBLK ((N_EDGES + PEPB - 1) / PEPB)     // 1042
#define OMS 784                                // offm row stride (782 bins + sentinel + pad)
#define RPT 5                                  // runs per thread in k_build (5*256 >= 1042)
#define NSK (NPB * 8)                          // sub-keys: node x 8 src-tiles

// ---------------- zero overflow cursor ----------------
__global__ void k_zero(int* __restrict__ ocur) {
    if (threadIdx.x == 0 && blockIdx.x == 0) *ocur = 0;
}

// ---------------- pass 1: per-block bin-grouped chunk + offset row ----------
// NO global atomics. Writes: offm row (contiguous 3KB) + grouped chunk
// (contiguous 24KB, full cache lines). The edge->bin transpose is deferred to
// k_build as scattered READS (no line ownership, cheap) instead of writes.
__global__ __launch_bounds__(256, 4) void k_part(
        const int* __restrict__ row, const int* __restrict__ col,
        const float* __restrict__ ew, int* __restrict__ offm,
        int2* __restrict__ chunks) {
    __shared__ int2 sed[PEPB];                 // 24576 B staged edges (grouped)
    __shared__ int shist[NBIN];                // counts -> local excl offsets
    __shared__ int scur[NBIN];                 // scan scratch, then cursors
    const int tid = threadIdx.x;
    const int blk = blockIdx.x;
    const int e0 = blk * PEPB;
    const int ne = min(PEPB, N_EDGES - e0);

    for (int i = tid; i < NBIN; i += 256) shist[i] = 0;
    __syncthreads();
    // histogram
    for (int i = tid; i < ne; i += 256) atomicAdd(&shist[col[e0 + i] >> 7], 1);
    __syncthreads();
    // block scan (4 bins/thread, scratch in scur[0..255])
    int l[4];
    int s = 0;
#pragma unroll
    for (int k = 0; k < 4; ++k) {
        int b = tid * 4 + k;
        l[k] = (b < NBIN) ? shist[b] : 0;
        s += l[k];
    }
    scur[tid] = s;
    __syncthreads();
    for (int d = 1; d < 256; d <<= 1) {
        int t = (tid >= d) ? scur[tid - d] : 0;
        __syncthreads();
        scur[tid] += t;
        __syncthreads();
    }
    int ex = scur[tid] - s;
    __syncthreads();  // scratch reads done before scur reused as cursors
#pragma unroll
    for (int k = 0; k < 4; ++k) {
        int b = tid * 4 + k;
        if (b < NBIN) {
            shist[b] = ex;                     // local exclusive offset
            scur[b] = ex;                      // cursor
            ex += l[k];
        }
    }
    __syncthreads();
    // write offset row (contiguous) + sentinel
    for (int b = tid; b < NBIN; b += 256) offm[blk * OMS + b] = shist[b];
    if (tid == 0) offm[blk * OMS + NBIN] = ne;
    // stage edges grouped by bin (LDS scatter)
    for (int i = tid; i < ne; i += 256) {
        int e = e0 + i;
        int c = col[e];
        int b = c >> 7;
        int p = atomicAdd(&scur[b], 1);        // LDS atomic
        sed[p] = make_int2(((c & (NPB - 1)) << 17) | row[e], __float_as_int(ew[e]));
    }
    __syncthreads();
    // contiguous full-line write-out
    for (int i = tid; i < ne; i += 256) chunks[(size_t)blk * PEPB + i] = sed[i];
}

// ---------------- pass 2: per-bin gather-from-chunks + group + deg + off2 ----
// Reads offm column (strided 4B) + run-gathers from chunks (scattered reads);
// all writes contiguous (binned CSR region) or tiny (off2, deg, binTot).
__global__ __launch_bounds__(256) void k_build(
        const int* __restrict__ offm, const int2* __restrict__ chunks,
        int2* __restrict__ binned, float* __restrict__ deg,
        int2* __restrict__ off2, int* __restrict__ binTot,
        int* __restrict__ ocur, int4* __restrict__ olist) {
    __shared__ int2 se[CAPB];                      // 36864 B
    __shared__ int scnt[NSK], scur2[NSK];          // 2 x 4096 B
    __shared__ float sdeg[NPB];
    __shared__ int spart[256];
    const int bin = blockIdx.x, tid = threadIdx.x;
    const size_t base = (size_t)bin * CAPB;

    for (int i = tid; i < NSK; i += 256) scnt[i] = 0;
    for (int i = tid; i < NPB; i += 256) sdeg[i] = 0.f;
    // load run extents (registers, static-indexed)
    int st[RPT], ln[RPT];
    int s = 0;
#pragma unroll
    for (int r = 0; r < RPT; ++r) {
        int k = tid * RPT + r;
        int a = 0, b2 = 0;
        if (k < PBLK) {
            a = offm[k * OMS + bin];
            b2 = offm[k * OMS + bin + 1];
        }
        st[r] = a;
        ln[r] = b2 - a;
        s += ln[r];
    }
    spart[tid] = s;
    __syncthreads();   // also orders scnt/sdeg init before gather atomics
    for (int d = 1; d < 256; d <<= 1) {
        int t = (tid >= d) ? spart[tid - d] : 0;
        __syncthreads();
        spart[tid] += t;
        __syncthreads();
    }
    int ex = spart[tid] - s;
    const int nTot = spart[255];
    const int n = min(nTot, CAPB);
    // gather runs into se; accumulate counts + weighted degree
    int dp = ex;
#pragma unroll
    for (int r = 0; r < RPT; ++r) {
        int k = tid * RPT + r;
        if (k < PBLK) {
            const int2* src = chunks + (size_t)k * PEPB + st[r];
            for (int j = 0; j < ln[r]; ++j) {
                int2 v = src[j];
                int lc = v.x >> 17;
                int dst = dp + j;
                if (dst < CAPB) {
                    se[dst] = v;
                    atomicAdd(&scnt[lc * 8 + ((v.x & 0x1FFFF) >> 14)], 1);
                    atomicAdd(&sdeg[lc], __int_as_float(v.y));
                } else {
                    int q = atomicAdd(ocur, 1);
                    if (q < OCAP)
                        olist[q] = make_int4(v.x & 0x1FFFF, bin * NPB + lc, v.y, 0);
                }
            }
            dp += ln[r];
        }
    }
    __syncthreads();
    // scan over 1024 sub-keys (4/thread, spart reused)
    int l0 = scnt[tid * 4], l1 = scnt[tid * 4 + 1],
        l2 = scnt[tid * 4 + 2], l3 = scnt[tid * 4 + 3];
    int s2 = l0 + l1 + l2 + l3;
    spart[tid] = s2;
    __syncthreads();
    for (int d = 1; d < 256; d <<= 1) {
        int t = (tid >= d) ? spart[tid - d] : 0;
        __syncthreads();
        spart[tid] += t;
        __syncthreads();
    }
    int ex2 = spart[tid] - s2;
    scnt[tid * 4] = ex2;
    scnt[tid * 4 + 1] = ex2 + l0;
    scnt[tid * 4 + 2] = ex2 + l0 + l1;
    scnt[tid * 4 + 3] = ex2 + l0 + l1 + l2;
    __syncthreads();
    for (int i = tid; i < NSK; i += 256) scur2[i] = scnt[i];
    __syncthreads();
    if (tid < NPB) {
        int node = bin * NPB + tid;
        if (node < N_NODES) {
            int stn = scnt[tid * 8];
            int en = (tid == NPB - 1) ? n : scnt[(tid + 1) * 8];
            off2[node] = make_int2((int)base + stn, en - stn);
            deg[node] = sdeg[tid] + 1.0f;  // + self loop
        }
    }
    if (tid == 0) binTot[bin] = n;
    __syncthreads();
    // regroup into final CSR {src, ew}
    for (int i = tid; i < n; i += 256) {
        int2 v = se[i];
        int lc = v.x >> 17, src2 = v.x & 0x1FFFF;
        int p = atomicAdd(&scur2[lc * 8 + (src2 >> 14)], 1);  // LDS atomic
        binned[base + p] = make_int2(src2, v.y);
    }
}

__global__ void k_degover(const int* __restrict__ ocur, const int4* __restrict__ olist,
                          float* __restrict__ deg) {
    int p = blockIdx.x * blockDim.x + threadIdx.x;
    int n = min(*ocur, OCAP);
    if (p < n) { int4 t = olist[p]; unsafeAtomicAdd(&deg[t.y], __int_as_float(t.z)); }
}

__global__ void k_dis(float* __restrict__ deg) {
    int i = blockIdx.x * blockDim.x + threadIdx.x;
    if (i < N_NODES) {
        float d = deg[i];
        deg[i] = (d > 0.0f) ? rsqrtf(d) : 0.0f;
    }
}

// ---------------- fold dis[src] into csr weights in-place ----------------
__global__ void k_wnorm(const int* __restrict__ binTot, int2* __restrict__ csr,
                        const float* __restrict__ dis) {
    int bin = blockIdx.x;
    int n = binTot[bin];
    size_t base = (size_t)bin * CAPB;
    for (int i = threadIdx.x; i < n; i += 256) {
        int2 v = csr[base + i];
        float w = __int_as_float(v.y) * dis[v.x];
        csr[base + i] = make_int2(v.x, __float_as_int(w));
    }
}

// ---------------- layer 1 GEMM: h = x @ W1^T (unchanged) ----------------
__global__ __launch_bounds__(256) void k_gemm1(
        const float* __restrict__ x, const float* __restrict__ W1,
        float* __restrict__ h) {
    __shared__ float sx[GR][GS];
    __shared__ float sw[HIDDEN][GS];

    const int tid = threadIdx.x;
    const size_t base = (size_t)blockIdx.x * GR;
    const float4* x4 = (const float4*)x;
    const float4* w4 = (const float4*)W1;

    const int r0 = tid >> 3;
    const int c0 = tid & 7;
    float acc[4][4] = {};

#pragma unroll
    for (int p = 0; p < 4; ++p) {
        for (int i = tid; i < GR * 16; i += 256) {
            int r = i >> 4, kq = i & 15;
            float4 v = make_float4(0.f, 0.f, 0.f, 0.f);
            if (base + r < N_NODES) v = x4[(base + r) * 64 + p * 16 + kq];
            *(float4*)&sx[r][kq * 4] = v;
        }
        for (int i = tid; i < HIDDEN * 16; i += 256) {
            int f = i >> 4, kq = i & 15;
            *(float4*)&sw[f][kq * 4] = w4[f * 64 + p * 16 + kq];
        }
        __syncthreads();

#pragma unroll 4
        for (int kq = 0; kq < 16; ++kq) {
            float4 xa[4], wv[4];
#pragma unroll
            for (int m = 0; m < 4; ++m) xa[m] = *(const float4*)&sx[r0 + 32 * m][kq * 4];
#pragma unroll
            for (int j = 0; j < 4; ++j) wv[j] = *(const float4*)&sw[c0 + 8 * j][kq * 4];
#pragma unroll
            for (int m = 0; m < 4; ++m)
#pragma unroll
                for (int j = 0; j < 4; ++j)
                    acc[m][j] += xa[m].x * wv[j].x + xa[m].y * wv[j].y +
                                 xa[m].z * wv[j].z + xa[m].w * wv[j].w;
        }
        __syncthreads();
    }

#pragma unroll
    for (int m = 0; m < 4; ++m) {
        size_t r = base + r0 + 32 * m;
        if (r < N_NODES) {
#pragma unroll
            for (int j = 0; j < 4; ++j) h[r * HIDDEN + c0 + 8 * j] = acc[m][j];
        }
    }
}

// ---- layer 1 gather: LDS-staged csr window (unchanged) ----
__global__ __launch_bounds__(256) void k_gather1(
        const int2* __restrict__ off2, const int2* __restrict__ csr,
        const float* __restrict__ h, const float* __restrict__ dis,
        const float* __restrict__ b1, float* __restrict__ out1) {
    __shared__ int2 sc[G1CAP];
    __shared__ int s_start, s_n;
    const int tid = threadIdx.x;
    const int node0 = blockIdx.x * G1N;
    if (tid == 0) {
        int2 a = off2[node0];
        int2 b = off2[node0 + G1N - 1];
        s_start = a.x;
        s_n = b.x + b.y - a.x;
    }
    __syncthreads();
    const int start = s_start, n = s_n;
    const bool fit = (n <= G1CAP);
    if (fit) for (int i = tid; i < n; i += 256) sc[i] = csr[start + i];
    __syncthreads();

    const int node = node0 + (tid >> 3);
    const int og = tid & 7;
    float d = dis[node];
    float d2 = d * d;
    float4 self = *(const float4*)(h + (size_t)node * HIDDEN + og * 4);
    float4 bv = *(const float4*)(b1 + og * 4);
    float4 acc = make_float4(0.f, 0.f, 0.f, 0.f);

    int2 o = off2[node];
    for (int j = 0; j < o.y; ++j) {
        int2 v = fit ? sc[o.x - start + j] : csr[o.x + j];
        float w = __int_as_float(v.y);
        const float4 hv = *(const float4*)(h + (size_t)v.x * HIDDEN + og * 4);
        acc.x += hv.x * w; acc.y += hv.y * w; acc.z += hv.z * w; acc.w += hv.w * w;
    }
    *(float4*)(out1 + (size_t)node * HIDDEN + og * 4) =
        make_float4(acc.x * d + self.x * d2 + bv.x, acc.y * d + self.y * d2 + bv.y,
                    acc.z * d + self.z * d2 + bv.z, acc.w * d + self.w * d2 + bv.w);
}

__global__ void k_over1(const int* __restrict__ ocur, const int4* __restrict__ olist,
                        const float* __restrict__ dis, const float* __restrict__ h,
                        float* __restrict__ out1) {
    int p = blockIdx.x * blockDim.x + threadIdx.x;
    int n = min(*ocur, OCAP);
    if (p < n) {
        int4 t = olist[p];
        int r = t.x, c = t.y;
        float w = dis[r] * __int_as_float(t.z) * dis[c];
        for (int f = 0; f < HIDDEN; ++f)
            unsafeAtomicAdd(&out1[(size_t)c * HIDDEN + f], h[(size_t)r * HIDDEN + f] * w);
    }
}

// ---------------- layer 2 GEMM: h2 = relu(out1) @ W2^T ----------------
__global__ void k_gemm2(const float* __restrict__ out1, const float* __restrict__ W2,
                        float* __restrict__ h2) {
    int t = blockIdx.x * blockDim.x + threadIdx.x;
    int i = t >> 4;
    if (i >= N_NODES) return;
    int f = t & 15;
    const float* r = out1 + (size_t)i * HIDDEN;
    const float* w = W2 + f * HIDDEN;
    float acc = 0.f;
#pragma unroll
    for (int k = 0; k < HIDDEN; ++k) acc += fmaxf(r[k], 0.f) * w[k];
    h2[(size_t)i * EMBED + f] = acc;
}

// ---- layer 2 gather: LDS-staged csr window (unchanged) ----
__global__ __launch_bounds__(256) void k_gather2(
        const int2* __restrict__ off2, const int2* __restrict__ csr,
        const float* __restrict__ h2, const float* __restrict__ dis,
        const float* __restrict__ b2, float* __restrict__ out) {
    __shared__ int2 sc[G2CAP];
    __shared__ int s_start, s_n;
    const int tid = threadIdx.x;
    const int node0 = blockIdx.x * G2N;
    const int lastn = min(node0 + G2N, N_NODES) - 1;
    if (tid == 0) {
        int2 a = off2[node0];
        int2 b = off2[lastn];
        s_start = a.x;
        s_n = b.x + b.y - a.x;
    }
    __syncthreads();
    const int start = s_start, n = s_n;
    const bool fit = (n <= G2CAP);
    if (fit) for (int i = tid; i < n; i += 256) sc[i] = csr[start + i];
    __syncthreads();

    const int node = node0 + (tid >> 2);
    const int og = tid & 3;
    if (node >= N_NODES) return;
    float d = dis[node];
    float d2 = d * d;
    float4 self = *(const float4*)(h2 + (size_t)node * EMBED + og * 4);
    float4 bv = *(const float4*)(b2 + og * 4);
    float4 acc = make_float4(0.f, 0.f, 0.f, 0.f);

    int2 o = off2[node];
    for (int j = 0; j < o.y; ++j) {
        int2 v = fit ? sc[o.x - start + j] : csr[o.x + j];
        float w = __int_as_float(v.y);
        const float4 hv = *(const float4*)(h2 + (size_t)v.x * EMBED + og * 4);
        acc.x += hv.x * w; acc.y += hv.y * w; acc.z += hv.z * w; acc.w += hv.w * w;
    }
    *(float4*)(out + (size_t)node * EMBED + og * 4) =
        make_float4(acc.x * d + self.x * d2 + bv.x, acc.y * d + self.y * d2 + bv.y,
                    acc.z * d + self.z * d2 + bv.z, acc.w * d + self.w * d2 + bv.w);
}

__global__ void k_over2(const int* __restrict__ ocur, const int4* __restrict__ olist,
                        const float* __restrict__ dis, const float* __restrict__ h2,
                        float* __restrict__ out) {
    int p = blockIdx.x * blockDim.x + threadIdx.x;
    int n = min(*ocur, OCAP);
    if (p < n) {
        int4 t = olist[p];
        int r = t.x, c = t.y;
        float w = dis[r] * __int_as_float(t.z) * dis[c];
        for (int f = 0; f < EMBED; ++f)
            unsafeAtomicAdd(&out[(size_t)c * EMBED + f], h2[(size_t)r * EMBED + f] * w);
    }
}

extern "C" void kernel_launch(void* const* d_in, const int* in_sizes, int n_in,
                              void* d_out, int out_size, void* d_ws, size_t ws_size,
                              hipStream_t stream) {
    const float* x  = (const float*)d_in[0];
    const int*   ei = (const int*)d_in[1];  // [2, E] int32
    const float* ew = (const float*)d_in[2];
    const float* W1 = (const float*)d_in[3];
    const float* b1 = (const float*)d_in[4];
    const float* W2 = (const float*)d_in[5];
    const float* b2 = (const float*)d_in[6];
    float* out = (float*)d_out;

    const int* row = ei;            // source
    const int* col = ei + N_EDGES;  // target

    // ws layout (all segment sizes 16B-aligned):
    // off2[N] int2 | binned[NBIN*CAPB] int2 | deg[N] f32 | binTot[784] int |
    // offm[PBLK*OMS] int | ocur[4] int | olist[OCAP] int4 |
    // big: chunks[PBLK*PEPB] int2  ALIASES  h[32N]+out1[32N]
    int2*  off2   = (int2*)d_ws;
    int2*  binned = off2 + N_NODES;
    float* deg    = (float*)(binned + (size_t)NBIN * CAPB);
    int*   binTot = (int*)(deg + N_NODES);
    int*   offm   = binTot + 784;
    int*   ocur   = offm + (size_t)PBLK * OMS;
    int4*  olist  = (int4*)(ocur + 4);
    void*  big    = (void*)(olist + OCAP);
    int2*  chunks = (int2*)big;
    float* h      = (float*)big;               // alias: chunks dead before gemm1
    float* out1   = h + (size_t)N_NODES * HIDDEN;
    float* h2     = h;                          // alias: h dead after over1

    const int B = 256;
    const int gN = (N_NODES + B - 1) / B;
    const int gO = (OCAP + B - 1) / B;

    k_zero<<<1, 64, 0, stream>>>(ocur);
    k_part<<<PBLK, B, 0, stream>>>(row, col, ew, offm, chunks);
    k_build<<<NBIN, B, 0, stream>>>(offm, chunks, binned, deg, off2, binTot, ocur, olist);
    k_degover<<<gO, B, 0, stream>>>(ocur, olist, deg);
    k_dis<<<gN, B, 0, stream>>>(deg);
    k_wnorm<<<NBIN, B, 0, stream>>>(binTot, binned, deg);
    k_gemm1<<<(N_NODES + GR - 1) / GR, B, 0, stream>>>(x, W1, h);
    k_gather1<<<N_NODES / G1N, B, 0, stream>>>(off2, binned, h, deg, b1, out1);
    k_over1<<<gO, B, 0, stream>>>(ocur, olist, deg, h, out1);
    k_gemm2<<<(N_NODES * 16 + B - 1) / B, B, 0, stream>>>(out1, W2, h2);
    k_gather2<<<(N_NODES + G2N - 1) / G2N, B, 0, stream>>>(off2, binned, h2, deg, b2, out);
    k_over2<<<gO, B, 0, stream>>>(ocur, olist, deg, h2, out);
}